// Round 9
// baseline (557.279 us; speedup 1.0000x reference)
//
#include <hip/hip_runtime.h>

// VQ-VAE VectorQuantizer: persistent LDS-resident fp16 codebook + MFMA scan,
// exact fp32 fallback. z: (32,64,64,64) NCHW fp32; codebook: (1024,64) fp32.
// d_out: [0]=loss, [1..]=z_q (NCHW).
//
// R17 (from R16 post-mortem): every chunked main is stall-dominated by the
// per-chunk barrier+vmcnt(0) drain (issue work ~6-8K cyc/wave vs ~45K cyc
// residency; VALUBusy 45% = SIMDs mostly idle). The fp16 codebook is only
// 128KB -> fits LDS. New main:
//  - 256 blocks x 512 thr = EXACTLY 1 block/CU (no tail), 512 queries/block.
//  - stage cbh(128KB)+norms(4KB) ONCE (hidden under z prologue), ONE barrier,
//    then a barrier-free scan of all 1024 codes: 64 t8-tiles, 8 MFMA + 2
//    ds_read_b128 + 64 track-VALU each, statically double-banked (bank0/bank1
//    named arrays -> no runtime indexing, rule #20) with deferred tracking.
//  - LDS 139KB static (128KB proven on this stack at m201; hw cap 160KB).
// Fix: R12-proven vq_fix verbatim (TAU=0.02, ~13K flags, L2-BW bound; only
// loss_part resized to 256). 3 launches. prep unchanged.

#define CB_N   1024
#define KDIM   64
#define HWD    4096
#define CHW    (KDIM * HWD)
#define NQ     131072
#define TOTALF 8388608.0f
#define TAU    0.02f
#define FCAP   16384
#define QPB    512            // queries per main block
#define NBLK   (NQ / QPB)     // 256 main blocks

typedef __attribute__((ext_vector_type(8))) _Float16 half8;
typedef __attribute__((ext_vector_type(4))) float    f32x4;

// async 16B/lane global->LDS copy (wave-uniform contiguous; m97 pattern)
__device__ __forceinline__ void gload_lds16(const void* g, void* l) {
    __builtin_amdgcn_global_load_lds(
        (const __attribute__((address_space(1))) unsigned int*)g,
        (__attribute__((address_space(3))) unsigned int*)l,
        16, 0, 0);
}

// ---------- ws layout (byte offsets) ----------
// 0: loss_adj  4: flag_cnt  8: done_cnt
// 128:    loss_part f32[256]
// 4224:   norms     f32[1024]
// 8320:   cbh_sw    u16[1024*64]   (fp16, rotate-swizzled row segments)
// 266368: flag_q i32[FCAP]  331904: flag_m1 f32[FCAP]  397440: flag_idx i32[FCAP]

// ---------------- prep: fp16 convert, swizzled rows, norms, counters --------
__global__ void vq_prep(const float* __restrict__ cb,
                        float* __restrict__ norms,
                        unsigned short* __restrict__ cbh,
                        float* __restrict__ loss_adj,
                        int* __restrict__ flag_cnt,
                        int* __restrict__ done_cnt) {
    const int tid = blockIdx.x * 256 + threadIdx.x;
    if (tid == 0) *loss_adj = 0.0f;
    if (tid == 1) *flag_cnt = 0;
    if (tid == 2) *done_cnt = 0;
    const int j  = tid >> 2;
    const int s2 = tid & 3;

    const float4* r4 = (const float4*)(cb + (size_t)j * KDIM);
    float s_norm = 0.0f;
    #pragma unroll
    for (int seg8 = 0; seg8 < 2; ++seg8) {
        const int s = s2 * 2 + seg8;
        float4 v0 = r4[s * 2 + 0];
        float4 v1 = r4[s * 2 + 1];
        float e[8] = {v0.x, v0.y, v0.z, v0.w, v1.x, v1.y, v1.z, v1.w};
        unsigned hh[4];
        #pragma unroll
        for (int c = 0; c < 8; ++c) {
            float x = e[c];
            s_norm = fmaf(x, x, s_norm);
            union { _Float16 h; unsigned short u; } cv;
            cv.h = (_Float16)x;                       // RNE fp16
            if ((c & 1) == 0) hh[c >> 1] = cv.u;
            else              hh[c >> 1] |= ((unsigned)cv.u) << 16;
        }
        const int p = (s + j) & 7;                    // bank-deconflict rotate
        *(uint4*)(cbh + (size_t)j * KDIM + p * 8) = make_uint4(hh[0], hh[1], hh[2], hh[3]);
    }
    s_norm += __shfl_xor(s_norm, 1, 64);
    s_norm += __shfl_xor(s_norm, 2, 64);
    if (s2 == 0) norms[j] = s_norm;
}

// ---- deferred min-tracking of a (statically named) bank -------------------
#define TRACK_BANK(BANKR)                                                    \
    {                                                                        \
        _Pragma("unroll")                                                    \
        for (int t = 0; t < 4; ++t) {                                        \
            _Pragma("unroll")                                                \
            for (int r = 0; r < 4; ++r) {                                    \
                float d = BANKR[t][r];                                       \
                bool cnd = d < m1[t][r];                                     \
                m2[t][r] = __builtin_amdgcn_fmed3f(d, m1[t][r], m2[t][r]);   \
                m1[t][r] = fminf(m1[t][r], d);                               \
                i1[t][r] = cnd ? prevCode : i1[t][r];                        \
            }                                                                \
        }                                                                    \
    }

// ---- one 16-code tile: ds_read B-frags, 8 MFMA into BANKW, update prevCode -
#define MFMA_STEP(BANKW, T8V)                                                \
    {                                                                        \
        const int crow = (T8V) * 16 + l16;                                   \
        const float nv = norms_s[crow];                                      \
        const half8 bh0 = *(const half8*)(&cb_s[crow * KDIM + p0]);          \
        const half8 bh1 = *(const half8*)(&cb_s[crow * KDIM + p1]);          \
        _Pragma("unroll")                                                    \
        for (int t = 0; t < 4; ++t) {                                        \
            f32x4 acc = {nv, nv, nv, nv};                                    \
            acc = __builtin_amdgcn_mfma_f32_16x16x32_f16(ah[t][0], bh0, acc, 0, 0, 0); \
            acc = __builtin_amdgcn_mfma_f32_16x16x32_f16(ah[t][1], bh1, acc, 0, 0, 0); \
            BANKW[t] = acc;                                                  \
        }                                                                    \
        prevCode = crow;                                                     \
    }

// ---------------- main: persistent LDS codebook, barrier-free scan ----------
__global__ __launch_bounds__(512, 2) void vq_main(
        const float* __restrict__ z,
        const float* __restrict__ cb,
        const unsigned short* __restrict__ cbh,
        const float* __restrict__ norms,
        float* __restrict__ out,
        float* __restrict__ loss_part,
        int* __restrict__ flag_q,
        float* __restrict__ flag_m1,
        int* __restrict__ flag_idx,
        int* __restrict__ flag_cnt) {
    __shared__ unsigned short cb_s[CB_N * KDIM];    // 128 KB, whole fp16 codebook
    __shared__ float          norms_s[CB_N];        // 4 KB
    __shared__ float          zn_s[QPB];            // 2 KB
    __shared__ int            idx_s[QPB];           // 2 KB
    __shared__ float          wsum_s[8];

    const int tid  = threadIdx.x;
    const int w    = tid >> 6;          // 8 waves
    const int lane = tid & 63;
    const int quad = lane >> 4;
    const int l16  = lane & 15;
    const int qb   = blockIdx.x * QPB;  // block's 512 queries (same batch b)
    const int b    = qb >> 12;
    const int hw0  = qb & 4095;

    // ---- stage the WHOLE fp16 codebook once (flies under the z prologue)
    {
        #pragma unroll
        for (int i = 0; i < 16; ++i) {
            const int off = i * 8192 + tid * 16;    // 16 x 8KB = 128 KB
            gload_lds16((const char*)cbh + off, (char*)cb_s + off);
        }
    }
    // ---- stage all code norms
    *(float4*)(norms_s + tid * 8)     = *(const float4*)(norms + tid * 8);
    *(float4*)(norms_s + tid * 8 + 4) = *(const float4*)(norms + tid * 8 + 4);

    // ---- stage A-frags: wave w owns queries [64w, 64w+64); 4 tiles of 16.
    const float* zbase = z + (size_t)b * CHW + hw0 + 64 * w;
    half8 ah[4][2];
    float znp[4] = {0.f, 0.f, 0.f, 0.f};
    #pragma unroll
    for (int t = 0; t < 4; ++t)
        #pragma unroll
        for (int ks = 0; ks < 2; ++ks)
            #pragma unroll
            for (int j = 0; j < 8; ++j) {
                float v = zbase[(size_t)(ks * 32 + quad * 8 + j) * HWD + t * 16 + l16];
                znp[t] = fmaf(v, v, znp[t]);
                ah[t][ks][j] = (_Float16)(-2.0f * v);   // RNE fp16
            }
    #pragma unroll
    for (int t = 0; t < 4; ++t) {
        znp[t] += __shfl_xor(znp[t], 16, 64);
        znp[t] += __shfl_xor(znp[t], 32, 64);
    }
    if (lane < 16)
        #pragma unroll
        for (int t = 0; t < 4; ++t)
            zn_s[64 * w + t * 16 + lane] = znp[t];

    float m1[4][4], m2[4][4];
    int   i1[4][4];
    #pragma unroll
    for (int t = 0; t < 4; ++t)
        #pragma unroll
        for (int r = 0; r < 4; ++r) { m1[t][r] = 3.4e38f; m2[t][r] = 3.4e38f; i1[t][r] = 0; }

    // loop-invariant swizzled segment offsets (ks=0 / ks=1); rows of cb_s are
    // rotate-swizzled by (s + j)&7 and (t8*16)%8==0 keeps the R12 formula.
    const int p0 = ((quad + l16) & 7) * 8;
    const int p1 = ((4 + quad + l16) & 7) * 8;

    f32x4 bank0[4], bank1[4];           // statically-named deferred banks
    int prevCode = 0;

    __syncthreads();                    // cb_s/norms_s/zn_s staged & visible

    // ---- barrier-free scan of all 64 tiles (codes 0..1023)
    MFMA_STEP(bank0, 0);                                // t8 = 0
    #pragma unroll 2
    for (int it = 0; it < 31; ++it) {
        {   // t8 = 2it+1 : track bank0 (tile 2it), write bank1
            const int t8v = 2 * it + 1;
            const int crow = t8v * 16 + l16;
            const float nv = norms_s[crow];
            const half8 bh0 = *(const half8*)(&cb_s[crow * KDIM + p0]);
            const half8 bh1 = *(const half8*)(&cb_s[crow * KDIM + p1]);
            TRACK_BANK(bank0);
            #pragma unroll
            for (int t = 0; t < 4; ++t) {
                f32x4 acc = {nv, nv, nv, nv};
                acc = __builtin_amdgcn_mfma_f32_16x16x32_f16(ah[t][0], bh0, acc, 0, 0, 0);
                acc = __builtin_amdgcn_mfma_f32_16x16x32_f16(ah[t][1], bh1, acc, 0, 0, 0);
                bank1[t] = acc;
            }
            prevCode = crow;
        }
        {   // t8 = 2it+2 : track bank1, write bank0
            const int t8v = 2 * it + 2;
            const int crow = t8v * 16 + l16;
            const float nv = norms_s[crow];
            const half8 bh0 = *(const half8*)(&cb_s[crow * KDIM + p0]);
            const half8 bh1 = *(const half8*)(&cb_s[crow * KDIM + p1]);
            TRACK_BANK(bank1);
            #pragma unroll
            for (int t = 0; t < 4; ++t) {
                f32x4 acc = {nv, nv, nv, nv};
                acc = __builtin_amdgcn_mfma_f32_16x16x32_f16(ah[t][0], bh0, acc, 0, 0, 0);
                acc = __builtin_amdgcn_mfma_f32_16x16x32_f16(ah[t][1], bh1, acc, 0, 0, 0);
                bank0[t] = acc;
            }
            prevCode = crow;
        }
    }
    {   // t8 = 63 : track bank0 (tile 62), write bank1
        const int crow = 63 * 16 + l16;
        const float nv = norms_s[crow];
        const half8 bh0 = *(const half8*)(&cb_s[crow * KDIM + p0]);
        const half8 bh1 = *(const half8*)(&cb_s[crow * KDIM + p1]);
        TRACK_BANK(bank0);
        #pragma unroll
        for (int t = 0; t < 4; ++t) {
            f32x4 acc = {nv, nv, nv, nv};
            acc = __builtin_amdgcn_mfma_f32_16x16x32_f16(ah[t][0], bh0, acc, 0, 0, 0);
            acc = __builtin_amdgcn_mfma_f32_16x16x32_f16(ah[t][1], bh1, acc, 0, 0, 0);
            bank1[t] = acc;
        }
        prevCode = crow;
    }
    TRACK_BANK(bank1);                                  // final deferred tile

    // ---- merge across 16 lanes (code residues), first-index ties
    #pragma unroll
    for (int s = 1; s < 16; s <<= 1)
        #pragma unroll
        for (int t = 0; t < 4; ++t)
            #pragma unroll
            for (int r = 0; r < 4; ++r) {
                float o1 = __shfl_xor(m1[t][r], s, 64);
                int   oi = __shfl_xor(i1[t][r], s, 64);
                float o2 = __shfl_xor(m2[t][r], s, 64);
                m2[t][r] = __builtin_amdgcn_fmed3f(m1[t][r], o1, fminf(m2[t][r], o2));
                if (o1 < m1[t][r] || (o1 == m1[t][r] && oi < i1[t][r])) {
                    m1[t][r] = o1; i1[t][r] = oi;
                }
            }

    // ---- owners (l16==0): publish idx, batched flags, loss partial
    float lsum = 0.0f;
    if (l16 == 0) {
        int nf = 0;
        #pragma unroll
        for (int t = 0; t < 4; ++t)
            #pragma unroll
            for (int r = 0; r < 4; ++r) {
                const int ql = 64 * w + t * 16 + quad * 4 + r;
                idx_s[ql] = i1[t][r];
                lsum += m1[t][r] + zn_s[ql];
                nf += (m2[t][r] - m1[t][r] < TAU) ? 1 : 0;
            }
        if (nf) {                      // ONE atomic per flagging owner thread
            int pos = atomicAdd(flag_cnt, nf);
            #pragma unroll
            for (int t = 0; t < 4; ++t)
                #pragma unroll
                for (int r = 0; r < 4; ++r)
                    if (m2[t][r] - m1[t][r] < TAU) {
                        if (pos < FCAP) {
                            flag_q[pos]   = qb + 64 * w + t * 16 + quad * 4 + r;
                            flag_m1[pos]  = m1[t][r];
                            flag_idx[pos] = i1[t][r];
                        }
                        ++pos;
                    }
        }
    }
    #pragma unroll
    for (int s = 1; s < 64; s <<= 1) lsum += __shfl_xor(lsum, s, 64);
    if (lane == 0) wsum_s[w] = lsum;
    __syncthreads();                   // idx_s + wsum_s visible

    // per-block loss partial: plain store, NO global atomic
    if (tid == 0) {
        float ls = 0.0f;
        #pragma unroll
        for (int wi = 0; wi < 8; ++wi) ls += wsum_s[wi];
        loss_part[blockIdx.x] = ls;
    }

    // ---- epilogue: thread tid -> query tid, all 64 channels (256B/wave/instr)
    {
        const int q   = tid;
        const int idx = idx_s[q];
        const float4* row = (const float4*)(cb + (size_t)idx * KDIM);
        float* op = out + 1 + (size_t)b * CHW + hw0 + q;
        #pragma unroll
        for (int i4 = 0; i4 < 16; ++i4) {
            float4 v = row[i4];
            op[(size_t)(i4 * 4 + 0) * HWD] = v.x;
            op[(size_t)(i4 * 4 + 1) * HWD] = v.y;
            op[(size_t)(i4 * 4 + 2) * HWD] = v.z;
            op[(size_t)(i4 * 4 + 3) * HWD] = v.w;
        }
    }
}

// ---------------- fix: exact fp32 re-rank for flagged queries + finalize ----
// lane = (code-in-pass lane>>2, dim-segment lane&3). Each lane holds 16 z dims
// in registers; cb loads are coalesced 16B chunks; two intra-quad shuffles
// finish each distance; 64 passes x 16 codes = all 1024 codes. (R12-proven.)
__global__ __launch_bounds__(256, 1) void vq_fix(
                       const float* __restrict__ z,
                       const float* __restrict__ cb,
                       float* __restrict__ out,
                       float* __restrict__ loss_adj,
                       const float* __restrict__ loss_part,
                       const int* __restrict__ flag_q,
                       const float* __restrict__ flag_m1,
                       const int* __restrict__ flag_idx,
                       const int* __restrict__ flag_cnt,
                       int* __restrict__ done_cnt) {
    __shared__ float red_s[4];
    __shared__ int   last_s;

    const int w    = threadIdx.x >> 6;
    const int lane = threadIdx.x & 63;
    const int seg  = lane & 3;          // 16-dim segment of the query
    const int cg   = lane >> 2;         // code-in-pass 0..15
    const int gw   = blockIdx.x * 4 + w;
    const int NW   = gridDim.x * 4;

    int n = *flag_cnt;
    if (n > FCAP) n = FCAP;

    for (int f = gw; f < n; f += NW) {
        const int   q   = flag_q[f];
        const float m1o = flag_m1[f];
        const int   io  = flag_idx[f];
        const int   b   = q >> 12;
        const int   hw  = q & 4095;

        // 16 register-resident z dims per lane (segment seg)
        float zq[16];
        float zpart = 0.0f;
        #pragma unroll
        for (int i = 0; i < 16; ++i) {
            zq[i] = z[(size_t)b * CHW + (size_t)(seg * 16 + i) * HWD + hw];
            zpart = fmaf(zq[i], zq[i], zpart);
        }
        float znorm = zpart;
        znorm += __shfl_xor(znorm, 1, 64);
        znorm += __shfl_xor(znorm, 2, 64);   // full ||z||^2 in every lane

        float best = 3.4e38f; int bj = 0;
        #pragma unroll 4
        for (int p = 0; p < 64; ++p) {
            const int j = p * 16 + cg;       // 64 passes x 16 codes = 1024
            const float4* rp = (const float4*)(cb + (size_t)j * KDIM + seg * 16);
            float d = 0.0f;
            #pragma unroll
            for (int q4 = 0; q4 < 4; ++q4) {
                float4 v = rp[q4];
                float t0 = zq[q4 * 4 + 0] - v.x;
                float t1 = zq[q4 * 4 + 1] - v.y;
                float t2 = zq[q4 * 4 + 2] - v.z;
                float t3 = zq[q4 * 4 + 3] - v.w;
                d = fmaf(t0, t0, d); d = fmaf(t1, t1, d);
                d = fmaf(t2, t2, d); d = fmaf(t3, t3, d);
            }
            d += __shfl_xor(d, 1, 64);
            d += __shfl_xor(d, 2, 64);       // full distance of code j (quad)
            if (d < best) { best = d; bj = j; }  // j ascends per lane: first-min
        }
        // reduce across 16 code-groups (quad lanes identical): steps 4..32
        #pragma unroll
        for (int s = 4; s < 64; s <<= 1) {
            float ob = __shfl_xor(best, s, 64);
            int   oj = __shfl_xor(bj, s, 64);
            if (ob < best || (ob == best && oj < bj)) { best = ob; bj = oj; }
        }
        if (bj != io) {
            out[1 + (size_t)b * CHW + (size_t)lane * HWD + hw] = cb[(size_t)bj * KDIM + lane];
            if (lane == 0) atomicAdd(loss_adj, best - (m1o + znorm));
        }
    }

    __syncthreads();
    if (threadIdx.x == 0) {
        __threadfence();
        last_s = (atomicAdd(done_cnt, 1) == (int)gridDim.x - 1) ? 1 : 0;
    }
    __syncthreads();

    if (last_s) {
        // all other blocks' loss_adj atomics + vq_main partials are visible
        float s = 0.0f;
        for (int i = threadIdx.x; i < NBLK; i += 256) s += loss_part[i];
        #pragma unroll
        for (int sh = 1; sh < 64; sh <<= 1) s += __shfl_xor(s, sh, 64);
        if (lane == 0) red_s[w] = s;
        __syncthreads();
        if (threadIdx.x == 0) {
            float L = red_s[0] + red_s[1] + red_s[2] + red_s[3]
                    + atomicAdd(loss_adj, 0.0f);
            out[0] = 1.25f * L / TOTALF;
        }
    }
}

extern "C" void kernel_launch(void* const* d_in, const int* in_sizes, int n_in,
                              void* d_out, int out_size, void* d_ws, size_t ws_size,
                              hipStream_t stream) {
    const float* z  = (const float*)d_in[0];
    const float* cb = (const float*)d_in[1];
    float* out      = (float*)d_out;
    char*  ws       = (char*)d_ws;

    float*          loss_adj  = (float*)(ws + 0);
    int*            flag_cnt  = (int*)(ws + 4);
    int*            done_cnt  = (int*)(ws + 8);
    float*          loss_part = (float*)(ws + 128);
    float*          norms     = (float*)(ws + 4224);
    unsigned short* cbh       = (unsigned short*)(ws + 8320);
    int*            flag_q    = (int*)(ws + 266368);
    float*          flag_m1   = (float*)(ws + 331904);
    int*            flag_idx  = (int*)(ws + 397440);

    vq_prep<<<dim3(16), dim3(256), 0, stream>>>(cb, norms, cbh,
                                                loss_adj, flag_cnt, done_cnt);

    vq_main<<<dim3(NBLK), dim3(512), 0, stream>>>(z, cb, cbh, norms, out,
                                                  loss_part, flag_q, flag_m1,
                                                  flag_idx, flag_cnt);

    vq_fix<<<dim3(256), dim3(256), 0, stream>>>(z, cb, out, loss_adj, loss_part,
                                                flag_q, flag_m1, flag_idx,
                                                flag_cnt, done_cnt);
}

// Round 10
// 198.916 us; speedup vs baseline: 2.8016x; 2.8016x over previous
//
#include <hip/hip_runtime.h>

// VQ-VAE VectorQuantizer: fp16 single-term MFMA distance + 8-flag-batched
// exact fp32 fallback. z: (32,64,64,64) NCHW fp32; codebook: (1024,64) fp32.
// d_out: [0]=loss, [1..]=z_q (NCHW).
//
// R18 (from R17 post-mortem): persistent-LDS main spilled (128-VGPR budget vs
// ~210 demand -> 1.1GB scratch, 484us). Reverted to the proven pieces:
//  - vq_prep + vq_main VERBATIM from R12/R16 (58us, VGPR 84, no spill).
//  - NEW vq_fix: the old fix's cost was ~13K flags x 256KB private L2
//    codebook scans (~3.3GB). Batch 8 flags per wave: 512 blocks x 256 thr
//    = 2048 waves, wave gw owns flags [8gw, 8gw+8) (2048*8 = FCAP: full
//    coverage, no stride loop). Same R12-proven lane mapping (seg=lane&3,
//    cg=lane>>2, 64 passes x 16 codes); each pass's 4 coalesced float4 cb
//    loads feed 8 distances (zq[8][16] register-resident, static indexing).
//    Codebook traffic /8; invalid tail flags mask writes/atomics.
//    __launch_bounds__(256,2) caps VGPR at 256 (demand ~210, no spill).

#define CB_N   1024
#define KDIM   64
#define HWD    4096
#define CHW    (KDIM * HWD)
#define NQ     131072
#define TOTALF 8388608.0f
#define TAU    0.02f
#define FCAP   16384
#define CHUNK  128            // codes per LDS chunk
#define NCHUNK (CB_N / CHUNK)

typedef __attribute__((ext_vector_type(8))) _Float16 half8;
typedef __attribute__((ext_vector_type(4))) float    f32x4;

// async 16B/lane global->LDS copy (wave-uniform contiguous; m97 pattern)
__device__ __forceinline__ void gload_lds16(const void* g, void* l) {
    __builtin_amdgcn_global_load_lds(
        (const __attribute__((address_space(1))) unsigned int*)g,
        (__attribute__((address_space(3))) unsigned int*)l,
        16, 0, 0);
}

// ---------- ws layout (byte offsets) ----------
// 0: loss_adj  4: flag_cnt  8: done_cnt
// 128:    loss_part f32[1024]
// 4224:   norms     f32[1024]
// 8320:   cbh_sw    u16[1024*64]   (fp16, rotate-swizzled row segments)
// 266368: flag_q i32[FCAP]  331904: flag_m1 f32[FCAP]  397440: flag_idx i32[FCAP]

// ---------------- prep: fp16 convert, swizzled rows, norms, counters --------
__global__ void vq_prep(const float* __restrict__ cb,
                        float* __restrict__ norms,
                        unsigned short* __restrict__ cbh,
                        float* __restrict__ loss_adj,
                        int* __restrict__ flag_cnt,
                        int* __restrict__ done_cnt) {
    const int tid = blockIdx.x * 256 + threadIdx.x;
    if (tid == 0) *loss_adj = 0.0f;
    if (tid == 1) *flag_cnt = 0;
    if (tid == 2) *done_cnt = 0;
    const int j  = tid >> 2;
    const int s2 = tid & 3;

    const float4* r4 = (const float4*)(cb + (size_t)j * KDIM);
    float s_norm = 0.0f;
    #pragma unroll
    for (int seg8 = 0; seg8 < 2; ++seg8) {
        const int s = s2 * 2 + seg8;
        float4 v0 = r4[s * 2 + 0];
        float4 v1 = r4[s * 2 + 1];
        float e[8] = {v0.x, v0.y, v0.z, v0.w, v1.x, v1.y, v1.z, v1.w};
        unsigned hh[4];
        #pragma unroll
        for (int c = 0; c < 8; ++c) {
            float x = e[c];
            s_norm = fmaf(x, x, s_norm);
            union { _Float16 h; unsigned short u; } cv;
            cv.h = (_Float16)x;                       // RNE fp16
            if ((c & 1) == 0) hh[c >> 1] = cv.u;
            else              hh[c >> 1] |= ((unsigned)cv.u) << 16;
        }
        const int p = (s + j) & 7;                    // bank-deconflict rotate
        *(uint4*)(cbh + (size_t)j * KDIM + p * 8) = make_uint4(hh[0], hh[1], hh[2], hh[3]);
    }
    s_norm += __shfl_xor(s_norm, 1, 64);
    s_norm += __shfl_xor(s_norm, 2, 64);
    if (s2 == 0) norms[j] = s_norm;
}

// ---------------- main (R12/R16 verbatim: 58us proven) ----------------------
__global__ __launch_bounds__(256, 3) void vq_main(
        const float* __restrict__ z,
        const float* __restrict__ cb,
        const unsigned short* __restrict__ cbh,
        const float* __restrict__ norms,
        float* __restrict__ out,
        float* __restrict__ loss_part,
        int* __restrict__ flag_q,
        float* __restrict__ flag_m1,
        int* __restrict__ flag_idx,
        int* __restrict__ flag_cnt) {
    __shared__ float          norms_s[CB_N];             // 4 KB
    __shared__ unsigned short bh_s[2][CHUNK * KDIM];     // 2 x 16 KB (dbuf)
    __shared__ float          zn_s[128];
    __shared__ int            idx_s[128];
    __shared__ float          wsum_s[4];

    const int tid  = threadIdx.x;
    const int w    = tid >> 6;
    const int lane = tid & 63;
    const int quad = lane >> 4;
    const int l16  = lane & 15;
    const int qb   = blockIdx.x * 128;     // block's 128 queries (same batch b)
    const int b    = qb >> 12;
    const int hw0  = qb & 4095;
    const int ch0  = blockIdx.x & (NCHUNK - 1);   // de-phase chunk start

    // ---- issue stage of chunk 0 FIRST (flies under the z-read prologue)
    {
        const char* gh = (const char*)cbh + (size_t)(ch0 & (NCHUNK - 1)) * (CHUNK * KDIM * 2);
        char* lh = (char*)(&bh_s[0][0]);
        #pragma unroll
        for (int i = 0; i < 4; ++i) {
            const int off = (w * 4 + i) * 1024 + lane * 16;
            gload_lds16(gh + off, lh + off);
        }
    }

    // ---- stage all code norms into LDS
    *(float4*)(norms_s + tid * 4) = *(const float4*)(norms + tid * 4);

    // ---- stage A-frags: wave w owns queries [32w, 32w+32); 2 tiles of 16.
    const float* zbase = z + (size_t)b * CHW + hw0 + 32 * w;
    half8 ah[2][2];
    float znp[2] = {0.f, 0.f};
    #pragma unroll
    for (int t = 0; t < 2; ++t)
        #pragma unroll
        for (int ks = 0; ks < 2; ++ks)
            #pragma unroll
            for (int j = 0; j < 8; ++j) {
                float v = zbase[(size_t)(ks * 32 + quad * 8 + j) * HWD + t * 16 + l16];
                znp[t] = fmaf(v, v, znp[t]);
                ah[t][ks][j] = (_Float16)(-2.0f * v);   // RNE fp16
            }
    #pragma unroll
    for (int t = 0; t < 2; ++t) {
        znp[t] += __shfl_xor(znp[t], 16, 64);
        znp[t] += __shfl_xor(znp[t], 32, 64);
    }
    if (lane < 16) {
        zn_s[32 * w + lane]      = znp[0];
        zn_s[32 * w + 16 + lane] = znp[1];
    }

    float m1[2][4], m2[2][4];
    int   i1[2][4];
    #pragma unroll
    for (int t = 0; t < 2; ++t)
        #pragma unroll
        for (int r = 0; r < 4; ++r) { m1[t][r] = 3.4e38f; m2[t][r] = 3.4e38f; i1[t][r] = 0; }

    // loop-invariant swizzled segment offsets (ks=0 / ks=1)
    const int p0 = ((quad + l16) & 7) * 8;
    const int p1 = ((4 + quad + l16) & 7) * 8;

    f32x4 bank[2][2];               // [tile-parity][t] -- deferred tracking
    bank[0][0] = bank[0][1] = (f32x4){0.f, 0.f, 0.f, 0.f};
    bank[1][0] = bank[1][1] = (f32x4){0.f, 0.f, 0.f, 0.f};
    int prevCode = 0;

    __syncthreads();                // chunk 0 staged + norms_s/zn_s visible
    int cur = 0;

    for (int cc = 0; cc < NCHUNK; ++cc) {
        // ---- issue next chunk's stage into the OTHER buffer (overlaps compute)
        if (cc + 1 < NCHUNK) {
            const int chn = (cc + 1 + ch0) & (NCHUNK - 1);
            const char* gh = (const char*)cbh + (size_t)chn * (CHUNK * KDIM * 2);
            char* lh = (char*)(&bh_s[cur ^ 1][0]);
            #pragma unroll
            for (int i = 0; i < 4; ++i) {
                const int off = (w * 4 + i) * 1024 + lane * 16;
                gload_lds16(gh + off, lh + off);
            }
        }

        const int ch = (cc + ch0) & (NCHUNK - 1);
        #pragma unroll
        for (int t8 = 0; t8 < 8; ++t8) {
            const int crow = t8 * 16 + l16;            // chunk-local code row
            const float nv = norms_s[ch * CHUNK + crow];
            const half8 bh0 = *(const half8*)(&bh_s[cur][crow * KDIM + p0]);
            const half8 bh1 = *(const half8*)(&bh_s[cur][crow * KDIM + p1]);
            const int code = ch * CHUNK + crow;
            const int bk = t8 & 1, pv = bk ^ 1;

            // track the DEFERRED tile (previous t8) held in bank[pv];
            // independent of bank[bk]'s MFMAs below -> overlaps them
            if (cc + t8 > 0) {
                #pragma unroll
                for (int t = 0; t < 2; ++t)
                    #pragma unroll
                    for (int r = 0; r < 4; ++r) {
                        float d = bank[pv][t][r];
                        bool cnd = d < m1[t][r];
                        m2[t][r] = __builtin_amdgcn_fmed3f(d, m1[t][r], m2[t][r]);
                        m1[t][r] = fminf(m1[t][r], d);
                        i1[t][r] = cnd ? prevCode : i1[t][r];
                    }
            }

            #pragma unroll
            for (int t = 0; t < 2; ++t) {
                f32x4 acc = {nv, nv, nv, nv};
                acc = __builtin_amdgcn_mfma_f32_16x16x32_f16(ah[t][0], bh0, acc, 0, 0, 0);
                acc = __builtin_amdgcn_mfma_f32_16x16x32_f16(ah[t][1], bh1, acc, 0, 0, 0);
                bank[bk][t] = acc;
            }
            prevCode = code;
        }

        __syncthreads();   // implicit vmcnt(0): next buffer landed; cur reads done
        cur ^= 1;
    }
    // final deferred tile (last t8=7 wrote bank[1])
    {
        #pragma unroll
        for (int t = 0; t < 2; ++t)
            #pragma unroll
            for (int r = 0; r < 4; ++r) {
                float d = bank[1][t][r];
                bool cnd = d < m1[t][r];
                m2[t][r] = __builtin_amdgcn_fmed3f(d, m1[t][r], m2[t][r]);
                m1[t][r] = fminf(m1[t][r], d);
                i1[t][r] = cnd ? prevCode : i1[t][r];
            }
    }

    // ---- merge across 16 lanes (code residues), first-index ties
    #pragma unroll
    for (int s = 1; s < 16; s <<= 1)
        #pragma unroll
        for (int t = 0; t < 2; ++t)
            #pragma unroll
            for (int r = 0; r < 4; ++r) {
                float o1 = __shfl_xor(m1[t][r], s, 64);
                int   oi = __shfl_xor(i1[t][r], s, 64);
                float o2 = __shfl_xor(m2[t][r], s, 64);
                m2[t][r] = __builtin_amdgcn_fmed3f(m1[t][r], o1, fminf(m2[t][r], o2));
                if (o1 < m1[t][r] || (o1 == m1[t][r] && oi < i1[t][r])) {
                    m1[t][r] = o1; i1[t][r] = oi;
                }
            }

    // ---- owners (l16==0): publish idx, batched flags, loss partial
    float lsum = 0.0f;
    if (l16 == 0) {
        int nf = 0;
        #pragma unroll
        for (int t = 0; t < 2; ++t)
            #pragma unroll
            for (int r = 0; r < 4; ++r) {
                const int ql = 32 * w + t * 16 + quad * 4 + r;
                idx_s[ql] = i1[t][r];
                lsum += m1[t][r] + zn_s[ql];
                nf += (m2[t][r] - m1[t][r] < TAU) ? 1 : 0;
            }
        if (nf) {                      // ONE atomic per flagging owner thread
            int pos = atomicAdd(flag_cnt, nf);
            #pragma unroll
            for (int t = 0; t < 2; ++t)
                #pragma unroll
                for (int r = 0; r < 4; ++r)
                    if (m2[t][r] - m1[t][r] < TAU) {
                        if (pos < FCAP) {
                            flag_q[pos]   = qb + 32 * w + t * 16 + quad * 4 + r;
                            flag_m1[pos]  = m1[t][r];
                            flag_idx[pos] = i1[t][r];
                        }
                        ++pos;
                    }
        }
    }
    #pragma unroll
    for (int s = 1; s < 64; s <<= 1) lsum += __shfl_xor(lsum, s, 64);
    if (lane == 0) wsum_s[w] = lsum;
    __syncthreads();                   // idx_s + wsum_s visible

    // per-block loss partial: plain store, NO global atomic
    if (tid == 0)
        loss_part[blockIdx.x] = wsum_s[0] + wsum_s[1] + wsum_s[2] + wsum_s[3];

    // ---- epilogue: thread -> (query tid&127, channels [32*(tid>>7),+32))
    {
        const int q   = tid & 127;
        const int cs  = (tid >> 7) * 32;
        const int idx = idx_s[q];
        const float4* row = (const float4*)(cb + (size_t)idx * KDIM + cs);
        float* op = out + 1 + (size_t)b * CHW + (size_t)cs * HWD + hw0 + q;
        #pragma unroll
        for (int i4 = 0; i4 < 8; ++i4) {
            float4 v = row[i4];
            op[(size_t)(i4 * 4 + 0) * HWD] = v.x;
            op[(size_t)(i4 * 4 + 1) * HWD] = v.y;
            op[(size_t)(i4 * 4 + 2) * HWD] = v.z;
            op[(size_t)(i4 * 4 + 3) * HWD] = v.w;
        }
    }
}

// ---------------- fix: 8-flag-batched exact fp32 re-rank + finalize ---------
// Wave gw owns flags [8gw, 8gw+8). lane = (code-in-pass lane>>2, dim-segment
// lane&3). zq[8][16] register-resident (static indexing); each pass's 4
// coalesced float4 cb loads feed 8 distances; two intra-quad shuffles finish
// each; 64 passes x 16 codes = all 1024 codes. First-min tie-break preserved
// (j ascends per lane; cross-lane reduce takes smaller j on ties).
__global__ __launch_bounds__(256, 2) void vq_fix(
                       const float* __restrict__ z,
                       const float* __restrict__ cb,
                       float* __restrict__ out,
                       float* __restrict__ loss_adj,
                       const float* __restrict__ loss_part,
                       const int* __restrict__ flag_q,
                       const float* __restrict__ flag_m1,
                       const int* __restrict__ flag_idx,
                       const int* __restrict__ flag_cnt,
                       int* __restrict__ done_cnt) {
    __shared__ float red_s[4];
    __shared__ int   last_s;

    const int w    = threadIdx.x >> 6;
    const int lane = threadIdx.x & 63;
    const int seg  = lane & 3;          // 16-dim segment of the query
    const int cg   = lane >> 2;         // code-in-pass 0..15
    const int gw   = blockIdx.x * 4 + w;   // 0..2047; 2048*8 = FCAP coverage

    int n = *flag_cnt;
    if (n > FCAP) n = FCAP;
    const int base = gw * 8;

    if (base < n) {
        // ---- load 8 flag records (clamped for the invalid tail)
        int fq[8]; float fm[8]; int fio[8];
        #pragma unroll
        for (int f = 0; f < 8; ++f) {
            const int idx = (base + f < n) ? base + f : base;
            fq[f]  = flag_q[idx];
            fm[f]  = flag_m1[idx];
            fio[f] = flag_idx[idx];
        }

        // ---- 8 register-resident z segments + norms
        float zq[8][16];
        float zn[8];
        #pragma unroll
        for (int f = 0; f < 8; ++f) {
            const int b  = fq[f] >> 12;
            const int hw = fq[f] & 4095;
            float s = 0.0f;
            #pragma unroll
            for (int i = 0; i < 16; ++i) {
                float v = z[(size_t)b * CHW + (size_t)(seg * 16 + i) * HWD + hw];
                zq[f][i] = v;
                s = fmaf(v, v, s);
            }
            s += __shfl_xor(s, 1, 64);
            s += __shfl_xor(s, 2, 64);       // full ||z||^2 in every lane
            zn[f] = s;
        }

        float best[8]; int bj[8];
        #pragma unroll
        for (int f = 0; f < 8; ++f) { best[f] = 3.4e38f; bj[f] = 0; }

        #pragma unroll 2
        for (int p = 0; p < 64; ++p) {
            const int j = p * 16 + cg;       // 64 passes x 16 codes = 1024
            const float4* rp = (const float4*)(cb + (size_t)j * KDIM + seg * 16);
            const float4 v0 = rp[0], v1 = rp[1], v2 = rp[2], v3 = rp[3];
            #pragma unroll
            for (int f = 0; f < 8; ++f) {
                float d = 0.0f, a;
                a = zq[f][ 0] - v0.x; d = fmaf(a, a, d);
                a = zq[f][ 1] - v0.y; d = fmaf(a, a, d);
                a = zq[f][ 2] - v0.z; d = fmaf(a, a, d);
                a = zq[f][ 3] - v0.w; d = fmaf(a, a, d);
                a = zq[f][ 4] - v1.x; d = fmaf(a, a, d);
                a = zq[f][ 5] - v1.y; d = fmaf(a, a, d);
                a = zq[f][ 6] - v1.z; d = fmaf(a, a, d);
                a = zq[f][ 7] - v1.w; d = fmaf(a, a, d);
                a = zq[f][ 8] - v2.x; d = fmaf(a, a, d);
                a = zq[f][ 9] - v2.y; d = fmaf(a, a, d);
                a = zq[f][10] - v2.z; d = fmaf(a, a, d);
                a = zq[f][11] - v2.w; d = fmaf(a, a, d);
                a = zq[f][12] - v3.x; d = fmaf(a, a, d);
                a = zq[f][13] - v3.y; d = fmaf(a, a, d);
                a = zq[f][14] - v3.z; d = fmaf(a, a, d);
                a = zq[f][15] - v3.w; d = fmaf(a, a, d);
                d += __shfl_xor(d, 1, 64);
                d += __shfl_xor(d, 2, 64);   // full distance of code j (quad)
                if (d < best[f]) { best[f] = d; bj[f] = j; }
            }
        }

        // ---- reduce across 16 code-groups; patch rows where exact differs
        #pragma unroll
        for (int f = 0; f < 8; ++f) {
            #pragma unroll
            for (int s = 4; s < 64; s <<= 1) {
                float ob = __shfl_xor(best[f], s, 64);
                int   oj = __shfl_xor(bj[f], s, 64);
                if (ob < best[f] || (ob == best[f] && oj < bj[f])) {
                    best[f] = ob; bj[f] = oj;
                }
            }
            if ((base + f < n) && bj[f] != fio[f]) {
                const int b  = fq[f] >> 12;
                const int hw = fq[f] & 4095;
                out[1 + (size_t)b * CHW + (size_t)lane * HWD + hw] =
                    cb[(size_t)bj[f] * KDIM + lane];
                if (lane == 0)
                    atomicAdd(loss_adj, best[f] - (fm[f] + zn[f]));
            }
        }
    }

    __syncthreads();
    if (threadIdx.x == 0) {
        __threadfence();
        last_s = (atomicAdd(done_cnt, 1) == (int)gridDim.x - 1) ? 1 : 0;
    }
    __syncthreads();

    if (last_s) {
        // all other blocks' loss_adj atomics + vq_main partials are visible
        float s = 0.0f;
        for (int i = threadIdx.x; i < 1024; i += 256) s += loss_part[i];
        #pragma unroll
        for (int sh = 1; sh < 64; sh <<= 1) s += __shfl_xor(s, sh, 64);
        if (lane == 0) red_s[w] = s;
        __syncthreads();
        if (threadIdx.x == 0) {
            float L = red_s[0] + red_s[1] + red_s[2] + red_s[3]
                    + atomicAdd(loss_adj, 0.0f);
            out[0] = 1.25f * L / TOTALF;
        }
    }
}

extern "C" void kernel_launch(void* const* d_in, const int* in_sizes, int n_in,
                              void* d_out, int out_size, void* d_ws, size_t ws_size,
                              hipStream_t stream) {
    const float* z  = (const float*)d_in[0];
    const float* cb = (const float*)d_in[1];
    float* out      = (float*)d_out;
    char*  ws       = (char*)d_ws;

    float*          loss_adj  = (float*)(ws + 0);
    int*            flag_cnt  = (int*)(ws + 4);
    int*            done_cnt  = (int*)(ws + 8);
    float*          loss_part = (float*)(ws + 128);
    float*          norms     = (float*)(ws + 4224);
    unsigned short* cbh       = (unsigned short*)(ws + 8320);
    int*            flag_q    = (int*)(ws + 266368);
    float*          flag_m1   = (float*)(ws + 331904);
    int*            flag_idx  = (int*)(ws + 397440);

    vq_prep<<<dim3(16), dim3(256), 0, stream>>>(cb, norms, cbh,
                                                loss_adj, flag_cnt, done_cnt);

    vq_main<<<dim3(NQ / 128), dim3(256), 0, stream>>>(z, cb, cbh, norms, out,
                                                      loss_part, flag_q, flag_m1,
                                                      flag_idx, flag_cnt);

    vq_fix<<<dim3(512), dim3(256), 0, stream>>>(z, cb, out, loss_adj, loss_part,
                                                flag_q, flag_m1, flag_idx,
                                                flag_cnt, done_cnt);
}

// Round 11
// 186.301 us; speedup vs baseline: 2.9913x; 1.0677x over previous
//
#include <hip/hip_runtime.h>

// VQ-VAE VectorQuantizer: fp16 single-term MFMA distance + 4-flag-batched
// exact fp32 fallback. z: (32,64,64,64) NCHW fp32; codebook: (1024,64) fp32.
// d_out: [0]=loss, [1..]=z_q (NCHW).
//
// R19 (from R18 post-mortem): B=8 batch spilled (demand ~200 vs 120 alloc ->
// zq in scratch, re-read 64x) and ownership-gating collapsed occupancy to 4%.
// Mechanism (amortize L2 loads over batched FMAs) is right; constants wrong:
//  - B=4: zq[4][16]=64 VGPR, total ~125 -> fits (256,2)'s 256 cap, NO spill.
//  - grid-stride batch loop over flags (2048 waves) -> load balance.
//  - unroll 2 on the pass loop: 32 float4s in flight, 128 FMA issued under
//    their latency -> ~0.85us/flag vs R12-fix's 3.3.
// vq_prep + vq_main verbatim (R12/R16-proven: 58us, VGPR 84, no spill).

#define CB_N   1024
#define KDIM   64
#define HWD    4096
#define CHW    (KDIM * HWD)
#define NQ     131072
#define TOTALF 8388608.0f
#define TAU    0.02f
#define FCAP   16384
#define CHUNK  128            // codes per LDS chunk
#define NCHUNK (CB_N / CHUNK)

typedef __attribute__((ext_vector_type(8))) _Float16 half8;
typedef __attribute__((ext_vector_type(4))) float    f32x4;

// async 16B/lane global->LDS copy (wave-uniform contiguous; m97 pattern)
__device__ __forceinline__ void gload_lds16(const void* g, void* l) {
    __builtin_amdgcn_global_load_lds(
        (const __attribute__((address_space(1))) unsigned int*)g,
        (__attribute__((address_space(3))) unsigned int*)l,
        16, 0, 0);
}

// ---------- ws layout (byte offsets) ----------
// 0: loss_adj  4: flag_cnt  8: done_cnt
// 128:    loss_part f32[1024]
// 4224:   norms     f32[1024]
// 8320:   cbh_sw    u16[1024*64]   (fp16, rotate-swizzled row segments)
// 266368: flag_q i32[FCAP]  331904: flag_m1 f32[FCAP]  397440: flag_idx i32[FCAP]

// ---------------- prep: fp16 convert, swizzled rows, norms, counters --------
__global__ void vq_prep(const float* __restrict__ cb,
                        float* __restrict__ norms,
                        unsigned short* __restrict__ cbh,
                        float* __restrict__ loss_adj,
                        int* __restrict__ flag_cnt,
                        int* __restrict__ done_cnt) {
    const int tid = blockIdx.x * 256 + threadIdx.x;
    if (tid == 0) *loss_adj = 0.0f;
    if (tid == 1) *flag_cnt = 0;
    if (tid == 2) *done_cnt = 0;
    const int j  = tid >> 2;
    const int s2 = tid & 3;

    const float4* r4 = (const float4*)(cb + (size_t)j * KDIM);
    float s_norm = 0.0f;
    #pragma unroll
    for (int seg8 = 0; seg8 < 2; ++seg8) {
        const int s = s2 * 2 + seg8;
        float4 v0 = r4[s * 2 + 0];
        float4 v1 = r4[s * 2 + 1];
        float e[8] = {v0.x, v0.y, v0.z, v0.w, v1.x, v1.y, v1.z, v1.w};
        unsigned hh[4];
        #pragma unroll
        for (int c = 0; c < 8; ++c) {
            float x = e[c];
            s_norm = fmaf(x, x, s_norm);
            union { _Float16 h; unsigned short u; } cv;
            cv.h = (_Float16)x;                       // RNE fp16
            if ((c & 1) == 0) hh[c >> 1] = cv.u;
            else              hh[c >> 1] |= ((unsigned)cv.u) << 16;
        }
        const int p = (s + j) & 7;                    // bank-deconflict rotate
        *(uint4*)(cbh + (size_t)j * KDIM + p * 8) = make_uint4(hh[0], hh[1], hh[2], hh[3]);
    }
    s_norm += __shfl_xor(s_norm, 1, 64);
    s_norm += __shfl_xor(s_norm, 2, 64);
    if (s2 == 0) norms[j] = s_norm;
}

// ---------------- main (R12/R16 verbatim: 58us proven) ----------------------
__global__ __launch_bounds__(256, 3) void vq_main(
        const float* __restrict__ z,
        const float* __restrict__ cb,
        const unsigned short* __restrict__ cbh,
        const float* __restrict__ norms,
        float* __restrict__ out,
        float* __restrict__ loss_part,
        int* __restrict__ flag_q,
        float* __restrict__ flag_m1,
        int* __restrict__ flag_idx,
        int* __restrict__ flag_cnt) {
    __shared__ float          norms_s[CB_N];             // 4 KB
    __shared__ unsigned short bh_s[2][CHUNK * KDIM];     // 2 x 16 KB (dbuf)
    __shared__ float          zn_s[128];
    __shared__ int            idx_s[128];
    __shared__ float          wsum_s[4];

    const int tid  = threadIdx.x;
    const int w    = tid >> 6;
    const int lane = tid & 63;
    const int quad = lane >> 4;
    const int l16  = lane & 15;
    const int qb   = blockIdx.x * 128;     // block's 128 queries (same batch b)
    const int b    = qb >> 12;
    const int hw0  = qb & 4095;
    const int ch0  = blockIdx.x & (NCHUNK - 1);   // de-phase chunk start

    // ---- issue stage of chunk 0 FIRST (flies under the z-read prologue)
    {
        const char* gh = (const char*)cbh + (size_t)(ch0 & (NCHUNK - 1)) * (CHUNK * KDIM * 2);
        char* lh = (char*)(&bh_s[0][0]);
        #pragma unroll
        for (int i = 0; i < 4; ++i) {
            const int off = (w * 4 + i) * 1024 + lane * 16;
            gload_lds16(gh + off, lh + off);
        }
    }

    // ---- stage all code norms into LDS
    *(float4*)(norms_s + tid * 4) = *(const float4*)(norms + tid * 4);

    // ---- stage A-frags: wave w owns queries [32w, 32w+32); 2 tiles of 16.
    const float* zbase = z + (size_t)b * CHW + hw0 + 32 * w;
    half8 ah[2][2];
    float znp[2] = {0.f, 0.f};
    #pragma unroll
    for (int t = 0; t < 2; ++t)
        #pragma unroll
        for (int ks = 0; ks < 2; ++ks)
            #pragma unroll
            for (int j = 0; j < 8; ++j) {
                float v = zbase[(size_t)(ks * 32 + quad * 8 + j) * HWD + t * 16 + l16];
                znp[t] = fmaf(v, v, znp[t]);
                ah[t][ks][j] = (_Float16)(-2.0f * v);   // RNE fp16
            }
    #pragma unroll
    for (int t = 0; t < 2; ++t) {
        znp[t] += __shfl_xor(znp[t], 16, 64);
        znp[t] += __shfl_xor(znp[t], 32, 64);
    }
    if (lane < 16) {
        zn_s[32 * w + lane]      = znp[0];
        zn_s[32 * w + 16 + lane] = znp[1];
    }

    float m1[2][4], m2[2][4];
    int   i1[2][4];
    #pragma unroll
    for (int t = 0; t < 2; ++t)
        #pragma unroll
        for (int r = 0; r < 4; ++r) { m1[t][r] = 3.4e38f; m2[t][r] = 3.4e38f; i1[t][r] = 0; }

    // loop-invariant swizzled segment offsets (ks=0 / ks=1)
    const int p0 = ((quad + l16) & 7) * 8;
    const int p1 = ((4 + quad + l16) & 7) * 8;

    f32x4 bank[2][2];               // [tile-parity][t] -- deferred tracking
    bank[0][0] = bank[0][1] = (f32x4){0.f, 0.f, 0.f, 0.f};
    bank[1][0] = bank[1][1] = (f32x4){0.f, 0.f, 0.f, 0.f};
    int prevCode = 0;

    __syncthreads();                // chunk 0 staged + norms_s/zn_s visible
    int cur = 0;

    for (int cc = 0; cc < NCHUNK; ++cc) {
        // ---- issue next chunk's stage into the OTHER buffer (overlaps compute)
        if (cc + 1 < NCHUNK) {
            const int chn = (cc + 1 + ch0) & (NCHUNK - 1);
            const char* gh = (const char*)cbh + (size_t)chn * (CHUNK * KDIM * 2);
            char* lh = (char*)(&bh_s[cur ^ 1][0]);
            #pragma unroll
            for (int i = 0; i < 4; ++i) {
                const int off = (w * 4 + i) * 1024 + lane * 16;
                gload_lds16(gh + off, lh + off);
            }
        }

        const int ch = (cc + ch0) & (NCHUNK - 1);
        #pragma unroll
        for (int t8 = 0; t8 < 8; ++t8) {
            const int crow = t8 * 16 + l16;            // chunk-local code row
            const float nv = norms_s[ch * CHUNK + crow];
            const half8 bh0 = *(const half8*)(&bh_s[cur][crow * KDIM + p0]);
            const half8 bh1 = *(const half8*)(&bh_s[cur][crow * KDIM + p1]);
            const int code = ch * CHUNK + crow;
            const int bk = t8 & 1, pv = bk ^ 1;

            // track the DEFERRED tile (previous t8) held in bank[pv];
            // independent of bank[bk]'s MFMAs below -> overlaps them
            if (cc + t8 > 0) {
                #pragma unroll
                for (int t = 0; t < 2; ++t)
                    #pragma unroll
                    for (int r = 0; r < 4; ++r) {
                        float d = bank[pv][t][r];
                        bool cnd = d < m1[t][r];
                        m2[t][r] = __builtin_amdgcn_fmed3f(d, m1[t][r], m2[t][r]);
                        m1[t][r] = fminf(m1[t][r], d);
                        i1[t][r] = cnd ? prevCode : i1[t][r];
                    }
            }

            #pragma unroll
            for (int t = 0; t < 2; ++t) {
                f32x4 acc = {nv, nv, nv, nv};
                acc = __builtin_amdgcn_mfma_f32_16x16x32_f16(ah[t][0], bh0, acc, 0, 0, 0);
                acc = __builtin_amdgcn_mfma_f32_16x16x32_f16(ah[t][1], bh1, acc, 0, 0, 0);
                bank[bk][t] = acc;
            }
            prevCode = code;
        }

        __syncthreads();   // implicit vmcnt(0): next buffer landed; cur reads done
        cur ^= 1;
    }
    // final deferred tile (last t8=7 wrote bank[1])
    {
        #pragma unroll
        for (int t = 0; t < 2; ++t)
            #pragma unroll
            for (int r = 0; r < 4; ++r) {
                float d = bank[1][t][r];
                bool cnd = d < m1[t][r];
                m2[t][r] = __builtin_amdgcn_fmed3f(d, m1[t][r], m2[t][r]);
                m1[t][r] = fminf(m1[t][r], d);
                i1[t][r] = cnd ? prevCode : i1[t][r];
            }
    }

    // ---- merge across 16 lanes (code residues), first-index ties
    #pragma unroll
    for (int s = 1; s < 16; s <<= 1)
        #pragma unroll
        for (int t = 0; t < 2; ++t)
            #pragma unroll
            for (int r = 0; r < 4; ++r) {
                float o1 = __shfl_xor(m1[t][r], s, 64);
                int   oi = __shfl_xor(i1[t][r], s, 64);
                float o2 = __shfl_xor(m2[t][r], s, 64);
                m2[t][r] = __builtin_amdgcn_fmed3f(m1[t][r], o1, fminf(m2[t][r], o2));
                if (o1 < m1[t][r] || (o1 == m1[t][r] && oi < i1[t][r])) {
                    m1[t][r] = o1; i1[t][r] = oi;
                }
            }

    // ---- owners (l16==0): publish idx, batched flags, loss partial
    float lsum = 0.0f;
    if (l16 == 0) {
        int nf = 0;
        #pragma unroll
        for (int t = 0; t < 2; ++t)
            #pragma unroll
            for (int r = 0; r < 4; ++r) {
                const int ql = 32 * w + t * 16 + quad * 4 + r;
                idx_s[ql] = i1[t][r];
                lsum += m1[t][r] + zn_s[ql];
                nf += (m2[t][r] - m1[t][r] < TAU) ? 1 : 0;
            }
        if (nf) {                      // ONE atomic per flagging owner thread
            int pos = atomicAdd(flag_cnt, nf);
            #pragma unroll
            for (int t = 0; t < 2; ++t)
                #pragma unroll
                for (int r = 0; r < 4; ++r)
                    if (m2[t][r] - m1[t][r] < TAU) {
                        if (pos < FCAP) {
                            flag_q[pos]   = qb + 32 * w + t * 16 + quad * 4 + r;
                            flag_m1[pos]  = m1[t][r];
                            flag_idx[pos] = i1[t][r];
                        }
                        ++pos;
                    }
        }
    }
    #pragma unroll
    for (int s = 1; s < 64; s <<= 1) lsum += __shfl_xor(lsum, s, 64);
    if (lane == 0) wsum_s[w] = lsum;
    __syncthreads();                   // idx_s + wsum_s visible

    // per-block loss partial: plain store, NO global atomic
    if (tid == 0)
        loss_part[blockIdx.x] = wsum_s[0] + wsum_s[1] + wsum_s[2] + wsum_s[3];

    // ---- epilogue: thread -> (query tid&127, channels [32*(tid>>7),+32))
    {
        const int q   = tid & 127;
        const int cs  = (tid >> 7) * 32;
        const int idx = idx_s[q];
        const float4* row = (const float4*)(cb + (size_t)idx * KDIM + cs);
        float* op = out + 1 + (size_t)b * CHW + (size_t)cs * HWD + hw0 + q;
        #pragma unroll
        for (int i4 = 0; i4 < 8; ++i4) {
            float4 v = row[i4];
            op[(size_t)(i4 * 4 + 0) * HWD] = v.x;
            op[(size_t)(i4 * 4 + 1) * HWD] = v.y;
            op[(size_t)(i4 * 4 + 2) * HWD] = v.z;
            op[(size_t)(i4 * 4 + 3) * HWD] = v.w;
        }
    }
}

// ---------------- fix: 4-flag-batched exact fp32 re-rank + finalize ---------
// Grid-stride batches of 4 flags per wave (2048 waves). lane = (code-in-pass
// lane>>2, dim-segment lane&3). zq[4][16] register-resident (static indexing,
// ~125 VGPR total -> no spill at (256,2)); each pass's 4 coalesced float4 cb
// loads feed 4 distances; two intra-quad shuffles finish each; 64 passes x 16
// codes = all 1024 codes. First-min tie-break preserved (j ascends per lane;
// cross-lane reduce takes smaller j on ties).
__global__ __launch_bounds__(256, 2) void vq_fix(
                       const float* __restrict__ z,
                       const float* __restrict__ cb,
                       float* __restrict__ out,
                       float* __restrict__ loss_adj,
                       const float* __restrict__ loss_part,
                       const int* __restrict__ flag_q,
                       const float* __restrict__ flag_m1,
                       const int* __restrict__ flag_idx,
                       const int* __restrict__ flag_cnt,
                       int* __restrict__ done_cnt) {
    __shared__ float red_s[4];
    __shared__ int   last_s;

    const int w    = threadIdx.x >> 6;
    const int lane = threadIdx.x & 63;
    const int seg  = lane & 3;          // 16-dim segment of the query
    const int cg   = lane >> 2;         // code-in-pass 0..15
    const int gw   = blockIdx.x * 4 + w;   // 0..2047
    const int NW   = gridDim.x * 4;        // 2048 waves

    int n = *flag_cnt;
    if (n > FCAP) n = FCAP;

    for (int base = gw * 4; base < n; base += NW * 4) {
        // ---- load 4 flag records (clamped for the tail)
        int fq[4]; float fm[4]; int fio[4];
        #pragma unroll
        for (int f = 0; f < 4; ++f) {
            const int idx = (base + f < n) ? base + f : base;
            fq[f]  = flag_q[idx];
            fm[f]  = flag_m1[idx];
            fio[f] = flag_idx[idx];
        }

        // ---- 4 register-resident z segments + norms
        float zq[4][16];
        float zn[4];
        #pragma unroll
        for (int f = 0; f < 4; ++f) {
            const int b  = fq[f] >> 12;
            const int hw = fq[f] & 4095;
            float s = 0.0f;
            #pragma unroll
            for (int i = 0; i < 16; ++i) {
                float v = z[(size_t)b * CHW + (size_t)(seg * 16 + i) * HWD + hw];
                zq[f][i] = v;
                s = fmaf(v, v, s);
            }
            s += __shfl_xor(s, 1, 64);
            s += __shfl_xor(s, 2, 64);       // full ||z||^2 in every lane
            zn[f] = s;
        }

        float best[4]; int bj[4];
        #pragma unroll
        for (int f = 0; f < 4; ++f) { best[f] = 3.4e38f; bj[f] = 0; }

        #pragma unroll 2
        for (int p = 0; p < 64; ++p) {
            const int j = p * 16 + cg;       // 64 passes x 16 codes = 1024
            const float4* rp = (const float4*)(cb + (size_t)j * KDIM + seg * 16);
            const float4 v0 = rp[0], v1 = rp[1], v2 = rp[2], v3 = rp[3];
            #pragma unroll
            for (int f = 0; f < 4; ++f) {
                float d = 0.0f, a;
                a = zq[f][ 0] - v0.x; d = fmaf(a, a, d);
                a = zq[f][ 1] - v0.y; d = fmaf(a, a, d);
                a = zq[f][ 2] - v0.z; d = fmaf(a, a, d);
                a = zq[f][ 3] - v0.w; d = fmaf(a, a, d);
                a = zq[f][ 4] - v1.x; d = fmaf(a, a, d);
                a = zq[f][ 5] - v1.y; d = fmaf(a, a, d);
                a = zq[f][ 6] - v1.z; d = fmaf(a, a, d);
                a = zq[f][ 7] - v1.w; d = fmaf(a, a, d);
                a = zq[f][ 8] - v2.x; d = fmaf(a, a, d);
                a = zq[f][ 9] - v2.y; d = fmaf(a, a, d);
                a = zq[f][10] - v2.z; d = fmaf(a, a, d);
                a = zq[f][11] - v2.w; d = fmaf(a, a, d);
                a = zq[f][12] - v3.x; d = fmaf(a, a, d);
                a = zq[f][13] - v3.y; d = fmaf(a, a, d);
                a = zq[f][14] - v3.z; d = fmaf(a, a, d);
                a = zq[f][15] - v3.w; d = fmaf(a, a, d);
                d += __shfl_xor(d, 1, 64);
                d += __shfl_xor(d, 2, 64);   // full distance of code j (quad)
                if (d < best[f]) { best[f] = d; bj[f] = j; }
            }
        }

        // ---- reduce across 16 code-groups; patch rows where exact differs
        #pragma unroll
        for (int f = 0; f < 4; ++f) {
            #pragma unroll
            for (int s = 4; s < 64; s <<= 1) {
                float ob = __shfl_xor(best[f], s, 64);
                int   oj = __shfl_xor(bj[f], s, 64);
                if (ob < best[f] || (ob == best[f] && oj < bj[f])) {
                    best[f] = ob; bj[f] = oj;
                }
            }
            if ((base + f < n) && bj[f] != fio[f]) {
                const int b  = fq[f] >> 12;
                const int hw = fq[f] & 4095;
                out[1 + (size_t)b * CHW + (size_t)lane * HWD + hw] =
                    cb[(size_t)bj[f] * KDIM + lane];
                if (lane == 0)
                    atomicAdd(loss_adj, best[f] - (fm[f] + zn[f]));
            }
        }
    }

    __syncthreads();
    if (threadIdx.x == 0) {
        __threadfence();
        last_s = (atomicAdd(done_cnt, 1) == (int)gridDim.x - 1) ? 1 : 0;
    }
    __syncthreads();

    if (last_s) {
        // all other blocks' loss_adj atomics + vq_main partials are visible
        float s = 0.0f;
        for (int i = threadIdx.x; i < 1024; i += 256) s += loss_part[i];
        #pragma unroll
        for (int sh = 1; sh < 64; sh <<= 1) s += __shfl_xor(s, sh, 64);
        if (lane == 0) red_s[w] = s;
        __syncthreads();
        if (threadIdx.x == 0) {
            float L = red_s[0] + red_s[1] + red_s[2] + red_s[3]
                    + atomicAdd(loss_adj, 0.0f);
            out[0] = 1.25f * L / TOTALF;
        }
    }
}

extern "C" void kernel_launch(void* const* d_in, const int* in_sizes, int n_in,
                              void* d_out, int out_size, void* d_ws, size_t ws_size,
                              hipStream_t stream) {
    const float* z  = (const float*)d_in[0];
    const float* cb = (const float*)d_in[1];
    float* out      = (float*)d_out;
    char*  ws       = (char*)d_ws;

    float*          loss_adj  = (float*)(ws + 0);
    int*            flag_cnt  = (int*)(ws + 4);
    int*            done_cnt  = (int*)(ws + 8);
    float*          loss_part = (float*)(ws + 128);
    float*          norms     = (float*)(ws + 4224);
    unsigned short* cbh       = (unsigned short*)(ws + 8320);
    int*            flag_q    = (int*)(ws + 266368);
    float*          flag_m1   = (float*)(ws + 331904);
    int*            flag_idx  = (int*)(ws + 397440);

    vq_prep<<<dim3(16), dim3(256), 0, stream>>>(cb, norms, cbh,
                                                loss_adj, flag_cnt, done_cnt);

    vq_main<<<dim3(NQ / 128), dim3(256), 0, stream>>>(z, cb, cbh, norms, out,
                                                      loss_part, flag_q, flag_m1,
                                                      flag_idx, flag_cnt);

    vq_fix<<<dim3(512), dim3(256), 0, stream>>>(z, cb, out, loss_adj, loss_part,
                                                flag_q, flag_m1, flag_idx,
                                                flag_cnt, done_cnt);
}

// Round 12
// 176.256 us; speedup vs baseline: 3.1618x; 1.0570x over previous
//
#include <hip/hip_runtime.h>

// VQ-VAE VectorQuantizer: fp16 hi/lo 3-term MFMA, NO-STAGING main (direct-L2
// B-fragments, zero in-loop barriers) + exact fp32 fallback.
// z: (32,64,64,64) NCHW fp32; codebook: (1024,64) fp32.
// d_out: [0]=loss, [1..]=z_q (NCHW).
//
// R20 (from R19 post-mortem): the fix at n~13-16K flags has a ~40us latency
// floor (3 attempts) -> the winning decomposition is 3-term main + tiny fix
// (R15: 91+5). The 91us main is stall-bound on per-chunk vmcnt(0)+barrier
// convoys at 8-wave lockstep. This round removes staging entirely:
//  - B-fragments read DIRECTLY from the L2-resident swizzled fp16 codebook
//    (half8 per lane, same 16B pattern the LDS read used; 1KB/instr).
//  - ZERO in-loop barriers; waves free-run. Hand prefetch: tile T+1's 4
//    fragments load while tile T's 12 MFMAs + tracking issue.
//  - LDS ~5.5KB (norms/zn/idx only) -> occupancy VGPR-bound: (256,3) ->
//    3 blocks/CU, 12 waves/CU (1.5x R15's 8).
//  - uniform scan order (no de-phase) -> all waves stream the same 256KB
//    sequence: L2 broadcast + L1 reuse.
// Keeps: R14 prep (hi/lo planes), TAU=1e-3 (n~250), batched flag atomics,
// R12/R14-proven vq_fix (~5us), per-block loss partials + done_cnt finalize.

#define CB_N   1024
#define KDIM   64
#define HWD    4096
#define CHW    (KDIM * HWD)
#define NQ     131072
#define TOTALF 8388608.0f
#define TAU    1.0e-3f
#define FCAP   16384

typedef __attribute__((ext_vector_type(8))) _Float16 half8;
typedef __attribute__((ext_vector_type(4))) float    f32x4;

// ---------- ws layout (byte offsets) ----------
// 0: loss_adj  4: flag_cnt  8: done_cnt
// 128:    loss_part f32[1024]
// 4224:   norms     f32[1024]
// 8320:   cbh_sw    u16[1024*64]   (fp16 hi, rotate-swizzled row segments)
// 139392: cbl_sw    u16[1024*64]   (fp16 lo, same swizzle)
// 270464: flag_q i32[FCAP]  336000: flag_m1 f32[FCAP]  401536: flag_idx i32[FCAP]

// ---------------- prep: fp16 hi/lo split, swizzled rows, norms, counters ----
__global__ void vq_prep(const float* __restrict__ cb,
                        float* __restrict__ norms,
                        unsigned short* __restrict__ cbh,
                        unsigned short* __restrict__ cbl,
                        float* __restrict__ loss_adj,
                        int* __restrict__ flag_cnt,
                        int* __restrict__ done_cnt) {
    const int tid = blockIdx.x * 256 + threadIdx.x;
    if (tid == 0) *loss_adj = 0.0f;
    if (tid == 1) *flag_cnt = 0;
    if (tid == 2) *done_cnt = 0;
    const int j  = tid >> 2;
    const int s2 = tid & 3;

    const float4* r4 = (const float4*)(cb + (size_t)j * KDIM);
    float s_norm = 0.0f;
    #pragma unroll
    for (int seg8 = 0; seg8 < 2; ++seg8) {
        const int s = s2 * 2 + seg8;
        float4 v0 = r4[s * 2 + 0];
        float4 v1 = r4[s * 2 + 1];
        float e[8] = {v0.x, v0.y, v0.z, v0.w, v1.x, v1.y, v1.z, v1.w};
        unsigned hh[4], ll[4];
        #pragma unroll
        for (int c = 0; c < 8; ++c) {
            float x = e[c];
            s_norm = fmaf(x, x, s_norm);
            union { _Float16 h; unsigned short u; } ch, cl;
            ch.h = (_Float16)x;                       // RNE fp16 hi
            cl.h = (_Float16)(x - (float)ch.h);       // RNE fp16 lo
            if ((c & 1) == 0) { hh[c >> 1] = ch.u;               ll[c >> 1] = cl.u; }
            else              { hh[c >> 1] |= ((unsigned)ch.u) << 16;
                                ll[c >> 1] |= ((unsigned)cl.u) << 16; }
        }
        const int p = (s + j) & 7;                    // bank-deconflict rotate
        *(uint4*)(cbh + (size_t)j * KDIM + p * 8) = make_uint4(hh[0], hh[1], hh[2], hh[3]);
        *(uint4*)(cbl + (size_t)j * KDIM + p * 8) = make_uint4(ll[0], ll[1], ll[2], ll[3]);
    }
    s_norm += __shfl_xor(s_norm, 1, 64);
    s_norm += __shfl_xor(s_norm, 2, 64);
    if (s2 == 0) norms[j] = s_norm;
}

// ---- deferred min-tracking of a statically named bank ----------------------
#define TRACK_BANK(BANKR)                                                    \
    {                                                                        \
        _Pragma("unroll")                                                    \
        for (int t = 0; t < 2; ++t) {                                        \
            _Pragma("unroll")                                                \
            for (int r = 0; r < 4; ++r) {                                    \
                float d = BANKR[t][r];                                       \
                bool cnd = d < m1[t][r];                                     \
                m2[t][r] = __builtin_amdgcn_fmed3f(d, m1[t][r], m2[t][r]);   \
                m1[t][r] = fminf(m1[t][r], d);                               \
                i1[t][r] = cnd ? prevCode : i1[t][r];                        \
            }                                                                \
        }                                                                    \
    }

// ---- 3-term MFMA for one tile into a named bank ----------------------------
#define MFMA_TILE(BANKW, H0, H1, L0, L1, NV)                                 \
    {                                                                        \
        _Pragma("unroll")                                                    \
        for (int t = 0; t < 2; ++t) {                                        \
            f32x4 acc = {(NV), (NV), (NV), (NV)};                            \
            acc = __builtin_amdgcn_mfma_f32_16x16x32_f16(ah[t][0], (H0), acc, 0, 0, 0); \
            acc = __builtin_amdgcn_mfma_f32_16x16x32_f16(al[t][0], (H0), acc, 0, 0, 0); \
            acc = __builtin_amdgcn_mfma_f32_16x16x32_f16(ah[t][0], (L0), acc, 0, 0, 0); \
            acc = __builtin_amdgcn_mfma_f32_16x16x32_f16(ah[t][1], (H1), acc, 0, 0, 0); \
            acc = __builtin_amdgcn_mfma_f32_16x16x32_f16(al[t][1], (H1), acc, 0, 0, 0); \
            acc = __builtin_amdgcn_mfma_f32_16x16x32_f16(ah[t][1], (L1), acc, 0, 0, 0); \
            BANKW[t] = acc;                                                  \
        }                                                                    \
    }

// ---------------- main: no staging, no in-loop barriers ---------------------
__global__ __launch_bounds__(256, 3) void vq_main(
        const float* __restrict__ z,
        const float* __restrict__ cb,
        const unsigned short* __restrict__ cbh,
        const unsigned short* __restrict__ cbl,
        const float* __restrict__ norms,
        float* __restrict__ out,
        float* __restrict__ loss_part,
        int* __restrict__ flag_q,
        float* __restrict__ flag_m1,
        int* __restrict__ flag_idx,
        int* __restrict__ flag_cnt) {
    __shared__ float norms_s[CB_N];     // 4 KB
    __shared__ float zn_s[128];
    __shared__ int   idx_s[128];
    __shared__ float wsum_s[4];

    const int tid  = threadIdx.x;
    const int w    = tid >> 6;
    const int lane = tid & 63;
    const int quad = lane >> 4;
    const int l16  = lane & 15;
    const int qb   = blockIdx.x * 128;     // block's 128 queries (same batch b)
    const int b    = qb >> 12;
    const int hw0  = qb & 4095;

    // ---- stage all code norms into LDS
    *(float4*)(norms_s + tid * 4) = *(const float4*)(norms + tid * 4);

    // ---- stage A-frags: wave w owns queries [32w, 32w+32); 2 tiles of 16.
    const float* zbase = z + (size_t)b * CHW + hw0 + 32 * w;
    half8 ah[2][2], al[2][2];
    float znp[2] = {0.f, 0.f};
    #pragma unroll
    for (int t = 0; t < 2; ++t)
        #pragma unroll
        for (int ks = 0; ks < 2; ++ks)
            #pragma unroll
            for (int j = 0; j < 8; ++j) {
                float v = zbase[(size_t)(ks * 32 + quad * 8 + j) * HWD + t * 16 + l16];
                znp[t] = fmaf(v, v, znp[t]);
                float s = -2.0f * v;
                _Float16 h = (_Float16)s;             // RNE fp16 hi
                ah[t][ks][j] = h;
                al[t][ks][j] = (_Float16)(s - (float)h);   // lo
            }
    #pragma unroll
    for (int t = 0; t < 2; ++t) {
        znp[t] += __shfl_xor(znp[t], 16, 64);
        znp[t] += __shfl_xor(znp[t], 32, 64);
    }
    if (lane < 16) {
        zn_s[32 * w + lane]      = znp[0];
        zn_s[32 * w + 16 + lane] = znp[1];
    }

    float m1[2][4], m2[2][4];
    int   i1[2][4];
    #pragma unroll
    for (int t = 0; t < 2; ++t)
        #pragma unroll
        for (int r = 0; r < 4; ++r) { m1[t][r] = 3.4e38f; m2[t][r] = 3.4e38f; i1[t][r] = 0; }

    // per-lane fragment byte offsets (rotate swizzle, R12 formula)
    const int b0 = ((quad + l16) & 7) * 16;        // p0 * 2 bytes
    const int b1 = ((4 + quad + l16) & 7) * 16;    // p1 * 2 bytes
    const char* hb = (const char*)cbh + (size_t)l16 * 128;
    const char* lb = (const char*)cbl + (size_t)l16 * 128;
    // tile T fragment: *(half8*)(hb + T*2048 + b0) etc.

    // ---- preload tile 0 into set A
    half8 Ah0 = *(const half8*)(hb + b0);
    half8 Ah1 = *(const half8*)(hb + b1);
    half8 Al0 = *(const half8*)(lb + b0);
    half8 Al1 = *(const half8*)(lb + b1);
    half8 Bh0, Bh1, Bl0, Bl1;

    f32x4 bank0[2], bank1[2];
    int prevCode = 0;

    __syncthreads();                    // norms_s visible

    // ---- barrier-free scan: 64 tiles, 2-phase (static banks), prefetched
    #pragma unroll 4
    for (int it = 0; it < 32; ++it) {
        const int tA = 2 * it;          // phase A tile (uses set A, writes bank0)
        {
            // prefetch tile tA+1 into set B (always exists: tA+1 <= 63)
            const size_t off = (size_t)(tA + 1) * 2048;
            Bh0 = *(const half8*)(hb + off + b0);
            Bh1 = *(const half8*)(hb + off + b1);
            Bl0 = *(const half8*)(lb + off + b0);
            Bl1 = *(const half8*)(lb + off + b1);
            const float nv = norms_s[tA * 16 + l16];
            if (it > 0) TRACK_BANK(bank1);          // tile tA-1
            MFMA_TILE(bank0, Ah0, Ah1, Al0, Al1, nv);
            prevCode = tA * 16 + l16;
        }
        {
            // phase B: tile tA+1 (uses set B, writes bank1); prefetch tA+2
            if (it < 31) {
                const size_t off = (size_t)(tA + 2) * 2048;
                Ah0 = *(const half8*)(hb + off + b0);
                Ah1 = *(const half8*)(hb + off + b1);
                Al0 = *(const half8*)(lb + off + b0);
                Al1 = *(const half8*)(lb + off + b1);
            }
            const float nv = norms_s[(tA + 1) * 16 + l16];
            TRACK_BANK(bank0);                      // tile tA
            MFMA_TILE(bank1, Bh0, Bh1, Bl0, Bl1, nv);
            prevCode = (tA + 1) * 16 + l16;
        }
    }
    TRACK_BANK(bank1);                              // final tile (63)

    // ---- merge across 16 lanes (code residues), first-index ties
    #pragma unroll
    for (int s = 1; s < 16; s <<= 1)
        #pragma unroll
        for (int t = 0; t < 2; ++t)
            #pragma unroll
            for (int r = 0; r < 4; ++r) {
                float o1 = __shfl_xor(m1[t][r], s, 64);
                int   oi = __shfl_xor(i1[t][r], s, 64);
                float o2 = __shfl_xor(m2[t][r], s, 64);
                m2[t][r] = __builtin_amdgcn_fmed3f(m1[t][r], o1, fminf(m2[t][r], o2));
                if (o1 < m1[t][r] || (o1 == m1[t][r] && oi < i1[t][r])) {
                    m1[t][r] = o1; i1[t][r] = oi;
                }
            }

    // ---- owners (l16==0): publish idx, batched flags, loss partial
    float lsum = 0.0f;
    if (l16 == 0) {
        int nf = 0;
        #pragma unroll
        for (int t = 0; t < 2; ++t)
            #pragma unroll
            for (int r = 0; r < 4; ++r) {
                const int ql = 32 * w + t * 16 + quad * 4 + r;
                idx_s[ql] = i1[t][r];
                lsum += m1[t][r] + zn_s[ql];
                nf += (m2[t][r] - m1[t][r] < TAU) ? 1 : 0;
            }
        if (nf) {                      // ONE atomic per flagging owner thread
            int pos = atomicAdd(flag_cnt, nf);
            #pragma unroll
            for (int t = 0; t < 2; ++t)
                #pragma unroll
                for (int r = 0; r < 4; ++r)
                    if (m2[t][r] - m1[t][r] < TAU) {
                        if (pos < FCAP) {
                            flag_q[pos]   = qb + 32 * w + t * 16 + quad * 4 + r;
                            flag_m1[pos]  = m1[t][r];
                            flag_idx[pos] = i1[t][r];
                        }
                        ++pos;
                    }
        }
    }
    #pragma unroll
    for (int s = 1; s < 64; s <<= 1) lsum += __shfl_xor(lsum, s, 64);
    if (lane == 0) wsum_s[w] = lsum;
    __syncthreads();                   // idx_s + wsum_s visible

    // per-block loss partial: plain store, NO global atomic
    if (tid == 0)
        loss_part[blockIdx.x] = wsum_s[0] + wsum_s[1] + wsum_s[2] + wsum_s[3];

    // ---- epilogue: thread -> (query tid&127, channels [32*(tid>>7),+32))
    {
        const int q   = tid & 127;
        const int cs  = (tid >> 7) * 32;
        const int idx = idx_s[q];
        const float4* row = (const float4*)(cb + (size_t)idx * KDIM + cs);
        float* op = out + 1 + (size_t)b * CHW + (size_t)cs * HWD + hw0 + q;
        #pragma unroll
        for (int i4 = 0; i4 < 8; ++i4) {
            float4 v = row[i4];
            op[(size_t)(i4 * 4 + 0) * HWD] = v.x;
            op[(size_t)(i4 * 4 + 1) * HWD] = v.y;
            op[(size_t)(i4 * 4 + 2) * HWD] = v.z;
            op[(size_t)(i4 * 4 + 3) * HWD] = v.w;
        }
    }
}

// ---------------- fix: exact fp32 re-rank for flagged queries + finalize ----
// lane = (code-in-pass lane>>2, dim-segment lane&3). 16 z dims/lane in regs;
// coalesced cb loads; quad shuffles finish distances; 64 passes x 16 codes.
// (R12/R14-proven; n~250 at TAU=1e-3 -> ~5us.)
__global__ __launch_bounds__(256, 1) void vq_fix(
                       const float* __restrict__ z,
                       const float* __restrict__ cb,
                       float* __restrict__ out,
                       float* __restrict__ loss_adj,
                       const float* __restrict__ loss_part,
                       const int* __restrict__ flag_q,
                       const float* __restrict__ flag_m1,
                       const int* __restrict__ flag_idx,
                       const int* __restrict__ flag_cnt,
                       int* __restrict__ done_cnt) {
    __shared__ float red_s[4];
    __shared__ int   last_s;

    const int w    = threadIdx.x >> 6;
    const int lane = threadIdx.x & 63;
    const int seg  = lane & 3;          // 16-dim segment of the query
    const int cg   = lane >> 2;         // code-in-pass 0..15
    const int gw   = blockIdx.x * 4 + w;
    const int NW   = gridDim.x * 4;

    int n = *flag_cnt;
    if (n > FCAP) n = FCAP;

    for (int f = gw; f < n; f += NW) {
        const int   q   = flag_q[f];
        const float m1o = flag_m1[f];
        const int   io  = flag_idx[f];
        const int   b   = q >> 12;
        const int   hw  = q & 4095;

        float zq[16];
        float zpart = 0.0f;
        #pragma unroll
        for (int i = 0; i < 16; ++i) {
            zq[i] = z[(size_t)b * CHW + (size_t)(seg * 16 + i) * HWD + hw];
            zpart = fmaf(zq[i], zq[i], zpart);
        }
        float znorm = zpart;
        znorm += __shfl_xor(znorm, 1, 64);
        znorm += __shfl_xor(znorm, 2, 64);   // full ||z||^2 in every lane

        float best = 3.4e38f; int bj = 0;
        #pragma unroll 4
        for (int p = 0; p < 64; ++p) {
            const int j = p * 16 + cg;       // 64 passes x 16 codes = 1024
            const float4* rp = (const float4*)(cb + (size_t)j * KDIM + seg * 16);
            float d = 0.0f;
            #pragma unroll
            for (int q4 = 0; q4 < 4; ++q4) {
                float4 v = rp[q4];
                float t0 = zq[q4 * 4 + 0] - v.x;
                float t1 = zq[q4 * 4 + 1] - v.y;
                float t2 = zq[q4 * 4 + 2] - v.z;
                float t3 = zq[q4 * 4 + 3] - v.w;
                d = fmaf(t0, t0, d); d = fmaf(t1, t1, d);
                d = fmaf(t2, t2, d); d = fmaf(t3, t3, d);
            }
            d += __shfl_xor(d, 1, 64);
            d += __shfl_xor(d, 2, 64);       // full distance of code j (quad)
            if (d < best) { best = d; bj = j; }  // j ascends per lane: first-min
        }
        #pragma unroll
        for (int s = 4; s < 64; s <<= 1) {
            float ob = __shfl_xor(best, s, 64);
            int   oj = __shfl_xor(bj, s, 64);
            if (ob < best || (ob == best && oj < bj)) { best = ob; bj = oj; }
        }
        if (bj != io) {
            out[1 + (size_t)b * CHW + (size_t)lane * HWD + hw] = cb[(size_t)bj * KDIM + lane];
            if (lane == 0) atomicAdd(loss_adj, best - (m1o + znorm));
        }
    }

    __syncthreads();
    if (threadIdx.x == 0) {
        __threadfence();
        last_s = (atomicAdd(done_cnt, 1) == (int)gridDim.x - 1) ? 1 : 0;
    }
    __syncthreads();

    if (last_s) {
        float s = 0.0f;
        for (int i = threadIdx.x; i < 1024; i += 256) s += loss_part[i];
        #pragma unroll
        for (int sh = 1; sh < 64; sh <<= 1) s += __shfl_xor(s, sh, 64);
        if (lane == 0) red_s[w] = s;
        __syncthreads();
        if (threadIdx.x == 0) {
            float L = red_s[0] + red_s[1] + red_s[2] + red_s[3]
                    + atomicAdd(loss_adj, 0.0f);
            out[0] = 1.25f * L / TOTALF;
        }
    }
}

extern "C" void kernel_launch(void* const* d_in, const int* in_sizes, int n_in,
                              void* d_out, int out_size, void* d_ws, size_t ws_size,
                              hipStream_t stream) {
    const float* z  = (const float*)d_in[0];
    const float* cb = (const float*)d_in[1];
    float* out      = (float*)d_out;
    char*  ws       = (char*)d_ws;

    float*          loss_adj  = (float*)(ws + 0);
    int*            flag_cnt  = (int*)(ws + 4);
    int*            done_cnt  = (int*)(ws + 8);
    float*          loss_part = (float*)(ws + 128);
    float*          norms     = (float*)(ws + 4224);
    unsigned short* cbh       = (unsigned short*)(ws + 8320);
    unsigned short* cbl       = (unsigned short*)(ws + 139392);
    int*            flag_q    = (int*)(ws + 270464);
    float*          flag_m1   = (float*)(ws + 336000);
    int*            flag_idx  = (int*)(ws + 401536);

    vq_prep<<<dim3(16), dim3(256), 0, stream>>>(cb, norms, cbh, cbl,
                                                loss_adj, flag_cnt, done_cnt);

    vq_main<<<dim3(NQ / 128), dim3(256), 0, stream>>>(z, cb, cbh, cbl, norms, out,
                                                      loss_part, flag_q, flag_m1,
                                                      flag_idx, flag_cnt);

    vq_fix<<<dim3(256), dim3(256), 0, stream>>>(z, cb, out, loss_adj, loss_part,
                                                flag_q, flag_m1, flag_idx,
                                                flag_cnt, done_cnt);
}